// Round 4
// baseline (54.091 us; speedup 1.0000x reference)
//
#include <hip/hip_runtime.h>
#include <math.h>

#define T_SEQ 2048
#define NH    16
#define HD    64
#define DIM   1024
#define WIN   256

typedef __attribute__((ext_vector_type(4))) float f32x4;
typedef __attribute__((ext_vector_type(8))) short s16x8;
typedef unsigned short u16;

static __device__ __forceinline__ u16 f2bf(float f) {
    unsigned u = __builtin_bit_cast(unsigned, f);
    u += 0x7fff + ((u >> 16) & 1);   // RNE; inputs finite
    return (u16)(u >> 16);
}

static __device__ __forceinline__ int fV(int d) { return (d & 7) ^ ((d >> 3) & 7); }

static __device__ __forceinline__ void gload16(const void* g, void* l) {
    __builtin_amdgcn_global_load_lds(
        (const __attribute__((address_space(1))) unsigned int*)g,
        (__attribute__((address_space(3))) unsigned int*)l, 16, 0, 0);
}

// ---------------------------------------------------------------------------
// W (K x N fp32) -> Wt (N x K bf16). Pad 69: read-side banks 2-way (free).
// ---------------------------------------------------------------------------
__global__ __launch_bounds__(256) void wconv_kernel(const float* __restrict__ W,
                                                    u16* __restrict__ Wt) {
    __shared__ float sT[64][69];
    const int t  = threadIdx.x;
    const int k0 = blockIdx.x * 64;
    const int n0 = blockIdx.y * 64;
#pragma unroll
    for (int i = 0; i < 4; ++i) {
        const int idx = i * 256 + t;
        const int kr = idx >> 4, c4 = (idx & 15) * 4;
        float4 v = *(const float4*)(W + (size_t)(k0 + kr) * DIM + n0 + c4);
        sT[kr][c4] = v.x; sT[kr][c4 + 1] = v.y; sT[kr][c4 + 2] = v.z; sT[kr][c4 + 3] = v.w;
    }
    __syncthreads();
#pragma unroll
    for (int i = 0; i < 2; ++i) {
        const int idx = i * 256 + t;
        const int nr = idx >> 3, ch = (idx & 7) * 8;
        s16x8 o;
#pragma unroll
        for (int e = 0; e < 8; ++e) o[e] = f2bf(sT[ch + e][nr]);
        *(s16x8*)(Wt + (size_t)(n0 + nr) * DIM + k0 + ch) = o;
    }
}

// ---------------------------------------------------------------------------
// Sliding-window attention, bf16 MFMA flash-style (unchanged from round 3).
// ---------------------------------------------------------------------------
__global__ __launch_bounds__(256) void attn_kernel(const float* __restrict__ qg,
                                                   const float* __restrict__ kg,
                                                   const float* __restrict__ vg,
                                                   u16* __restrict__ y) {
    __shared__ __align__(16) char sK[64 * 128];
    __shared__ __align__(16) char sV[64 * 128];
    __shared__ __align__(16) char sP[4][16 * 128];

    const int t    = threadIdx.x;
    const int lane = t & 63;
    const int w    = t >> 6;
    const int q0   = blockIdx.x * 64;
    const int h    = blockIdx.y;
    const size_t headBase = (size_t)h * T_SEQ * HD;

    const int lr = lane & 15;
    const int lg = lane >> 4;

    s16x8 qf[2];
    {
        const float* qrow = qg + headBase + (size_t)(q0 + w * 16 + lr) * HD + lg * 8;
#pragma unroll
        for (int s = 0; s < 2; ++s) {
            float4 a = *(const float4*)(qrow + 32 * s);
            float4 b = *(const float4*)(qrow + 32 * s + 4);
            s16x8 f;
            f[0] = f2bf(a.x); f[1] = f2bf(a.y); f[2] = f2bf(a.z); f[3] = f2bf(a.w);
            f[4] = f2bf(b.x); f[5] = f2bf(b.y); f[6] = f2bf(b.z); f[7] = f2bf(b.w);
            qf[s] = f;
        }
    }

    f32x4 o[4];
#pragma unroll
    for (int i = 0; i < 4; ++i) o[i] = (f32x4){0.f, 0.f, 0.f, 0.f};
    float lsum[4] = {0.f, 0.f, 0.f, 0.f};

    int lo = q0 - (WIN - 1);
    if (lo < 0) lo = 0;
    const int kc0 = lo & ~63;

    const int srow = t >> 2;
    const int sd0  = (t & 3) * 16;

    for (int kc = kc0; kc <= q0; kc += 64) {
        __syncthreads();
        {
            const float* ksrc = kg + headBase + (size_t)(kc + srow) * HD + sd0;
            float4 k0 = *(const float4*)(ksrc);
            float4 k1 = *(const float4*)(ksrc + 4);
            float4 k2 = *(const float4*)(ksrc + 8);
            float4 k3 = *(const float4*)(ksrc + 12);
            s16x8 c0, c1;
            c0[0] = f2bf(k0.x); c0[1] = f2bf(k0.y); c0[2] = f2bf(k0.z); c0[3] = f2bf(k0.w);
            c0[4] = f2bf(k1.x); c0[5] = f2bf(k1.y); c0[6] = f2bf(k1.z); c0[7] = f2bf(k1.w);
            c1[0] = f2bf(k2.x); c1[1] = f2bf(k2.y); c1[2] = f2bf(k2.z); c1[3] = f2bf(k2.w);
            c1[4] = f2bf(k3.x); c1[5] = f2bf(k3.y); c1[6] = f2bf(k3.z); c1[7] = f2bf(k3.w);
            const int swz = (srow & 7) << 4;
            *(s16x8*)(sK + srow * 128 + ((sd0 * 2) ^ swz))      = c0;
            *(s16x8*)(sK + srow * 128 + ((sd0 * 2 + 16) ^ swz)) = c1;

            const float* vsrc = vg + headBase + (size_t)(kc + srow) * HD + sd0;
            float4 v0 = *(const float4*)(vsrc);
            float4 v1 = *(const float4*)(vsrc + 4);
            float4 v2 = *(const float4*)(vsrc + 8);
            float4 v3 = *(const float4*)(vsrc + 12);
            float vv[16] = {v0.x, v0.y, v0.z, v0.w, v1.x, v1.y, v1.z, v1.w,
                            v2.x, v2.y, v2.z, v2.w, v3.x, v3.y, v3.z, v3.w};
#pragma unroll
            for (int e = 0; e < 16; ++e) {
                const int d = sd0 + e;
                *(u16*)(sV + d * 128 + ((srow * 2) ^ (fV(d) << 4))) = f2bf(vv[e]);
            }
        }
        __syncthreads();

        char* pw = sP[w];
#pragma unroll
        for (int kt = 0; kt < 4; ++kt) {
            const int krow = kt * 16 + lr;
            const int kswz = (krow & 7) << 4;
            s16x8 kf0 = *(const s16x8*)(sK + krow * 128 + ((lg * 16) ^ kswz));
            s16x8 kf1 = *(const s16x8*)(sK + krow * 128 + ((lg * 16 + 64) ^ kswz));
            f32x4 s = (f32x4){0.f, 0.f, 0.f, 0.f};
            s = __builtin_amdgcn_mfma_f32_16x16x32_bf16(qf[0], kf0, s, 0, 0, 0);
            s = __builtin_amdgcn_mfma_f32_16x16x32_bf16(qf[1], kf1, s, 0, 0, 0);
            const int key = kc + kt * 16 + lr;
#pragma unroll
            for (int r = 0; r < 4; ++r) {
                const int qrow = q0 + w * 16 + lg * 4 + r;
                float pv = 0.f;
                if (key <= qrow && key > qrow - WIN) pv = __expf(s[r] * 0.125f);
                lsum[r] += pv;
                const int prow = lg * 4 + r;
                *(u16*)(pw + prow * 128 + ((kt * 32 + lr * 2) ^ ((prow & 7) << 4))) = f2bf(pv);
            }
        }

        s16x8 pf0 = *(const s16x8*)(pw + lr * 128 + ((lg * 16) ^ ((lr & 7) << 4)));
        s16x8 pf1 = *(const s16x8*)(pw + lr * 128 + ((lg * 16 + 64) ^ ((lr & 7) << 4)));
#pragma unroll
        for (int td = 0; td < 4; ++td) {
            const int drow = td * 16 + lr;
            const int vswz = fV(drow) << 4;
            s16x8 vf0 = *(const s16x8*)(sV + drow * 128 + ((lg * 16) ^ vswz));
            s16x8 vf1 = *(const s16x8*)(sV + drow * 128 + ((lg * 16 + 64) ^ vswz));
            o[td] = __builtin_amdgcn_mfma_f32_16x16x32_bf16(pf0, vf0, o[td], 0, 0, 0);
            o[td] = __builtin_amdgcn_mfma_f32_16x16x32_bf16(pf1, vf1, o[td], 0, 0, 0);
        }
    }

#pragma unroll
    for (int m = 1; m < 16; m <<= 1) {
#pragma unroll
        for (int r = 0; r < 4; ++r) lsum[r] += __shfl_xor(lsum[r], m, 64);
    }
    float rl[4];
#pragma unroll
    for (int r = 0; r < 4; ++r) rl[r] = 1.f / lsum[r];
#pragma unroll
    for (int td = 0; td < 4; ++td)
#pragma unroll
        for (int r = 0; r < 4; ++r)
            y[(size_t)(q0 + w * 16 + lg * 4 + r) * DIM + h * HD + td * 16 + lr] =
                f2bf(o[td][r] * rl[r]);
}

// ---------------------------------------------------------------------------
// proj: out = y @ W. BM=BN=BK=64, 4 waves (2x2), wave-tile 32x32.
// 512 blocks (2/CU) with XCD-chunked bijective swizzle: each XCD gets 64
// contiguous wgids = 4 M-panels x 16 N-panels -> 2.5MB L2 footprint.
// ---------------------------------------------------------------------------
__global__ __launch_bounds__(256) void proj_kernel(const u16* __restrict__ A,
                                                   const u16* __restrict__ Bt,
                                                   float* __restrict__ out) {
    __shared__ __align__(16) char sA[2][64 * 128];  // [m][k] bf16, 8KB each
    __shared__ __align__(16) char sB[2][64 * 128];  // [n][k] bf16, 8KB each

    const int t    = threadIdx.x;
    const int lane = t & 63;
    const int w    = t >> 6;
    const int wr   = w >> 1, wc = w & 1;
    const int lr   = lane & 15, lg = lane >> 4;

    // XCD-chunked bijective swizzle (nwg=512, 8 XCDs, q=64, r=0)
    const int id   = (int)blockIdx.x;
    const int wgid = (id & 7) * 64 + (id >> 3);
    const int m0   = (wgid >> 4) * 64;   // by * 64, by in [0,32)
    const int n0   = (wgid & 15) * 64;   // bx * 64, bx in [0,16)

    f32x4 acc[2][2];
#pragma unroll
    for (int i = 0; i < 2; ++i)
#pragma unroll
        for (int j = 0; j < 2; ++j) acc[i][j] = (f32x4){0.f, 0.f, 0.f, 0.f};

    // staging geometry: wave w covers rows [p*32 + w*8, +8), lane chunk = lane&7
    const int aRowBase = w * 8 + (lane >> 3);
    const int aChunk   = lane & 7;

#define STAGE(buf, k0)                                                                \
    do {                                                                              \
        _Pragma("unroll") for (int p = 0; p < 2; ++p) {                               \
            const int row = p * 32 + aRowBase;                                        \
            gload16(A + (size_t)(m0 + row) * DIM + (k0) + ((aChunk ^ (row & 7)) << 3),\
                    sA[buf] + p * 4096 + w * 1024);                                   \
            gload16(Bt + (size_t)(n0 + row) * DIM + (k0) + ((aChunk ^ (row & 7)) << 3),\
                    sB[buf] + p * 4096 + w * 1024);                                   \
        }                                                                             \
    } while (0)

    STAGE(0, 0);
    __syncthreads();

    for (int kt = 0; kt < DIM / 64; ++kt) {
        const int buf = kt & 1;
        if (kt < DIM / 64 - 1) STAGE(buf ^ 1, (kt + 1) * 64);

        s16x8 af[2][2], bfr[2][2];
#pragma unroll
        for (int kh = 0; kh < 2; ++kh) {
#pragma unroll
            for (int mi = 0; mi < 2; ++mi) {
                const int row = wr * 32 + mi * 16 + lr;
                const int cc  = kh * 4 + lg;
                af[kh][mi] = *(const s16x8*)(sA[buf] + row * 128 + ((cc ^ (row & 7)) << 4));
            }
#pragma unroll
            for (int ni = 0; ni < 2; ++ni) {
                const int row = wc * 32 + ni * 16 + lr;
                const int cc  = kh * 4 + lg;
                bfr[kh][ni] = *(const s16x8*)(sB[buf] + row * 128 + ((cc ^ (row & 7)) << 4));
            }
        }
#pragma unroll
        for (int kh = 0; kh < 2; ++kh)
#pragma unroll
            for (int mi = 0; mi < 2; ++mi)
#pragma unroll
                for (int ni = 0; ni < 2; ++ni)
                    acc[mi][ni] = __builtin_amdgcn_mfma_f32_16x16x32_bf16(
                        af[kh][mi], bfr[kh][ni], acc[mi][ni], 0, 0, 0);
        __syncthreads();
    }
#undef STAGE

#pragma unroll
    for (int mi = 0; mi < 2; ++mi)
#pragma unroll
        for (int ni = 0; ni < 2; ++ni)
#pragma unroll
            for (int r = 0; r < 4; ++r)
                out[(size_t)(m0 + wr * 32 + mi * 16 + lg * 4 + r) * DIM +
                    n0 + wc * 32 + ni * 16 + lr] = acc[mi][ni][r];
}

extern "C" void kernel_launch(void* const* d_in, const int* in_sizes, int n_in,
                              void* d_out, int out_size, void* d_ws, size_t ws_size,
                              hipStream_t stream) {
    const float* q = (const float*)d_in[0];
    const float* k = (const float*)d_in[1];
    const float* v = (const float*)d_in[2];
    const float* W = (const float*)d_in[3];
    float* out = (float*)d_out;
    u16* y_bf = (u16*)d_ws;                       // (T, DIM) bf16 = 4MB
    u16* Wt   = (u16*)d_ws + (size_t)T_SEQ * DIM; // (DIM, DIM) bf16 = 2MB

    dim3 gW(DIM / 64, DIM / 64);
    wconv_kernel<<<gW, 256, 0, stream>>>(W, Wt);

    dim3 gA(T_SEQ / 64, NH);
    attn_kernel<<<gA, 256, 0, stream>>>(q, k, v, y_bf);

    // Launched twice deliberately (deterministic, identical output): with C =
    // wconv+attn+gaps ~ 9-10us known, total = C + p_cold + p_warm solves proj's
    // true duration from dur_us alone. Round 5 drops the duplicate.
    proj_kernel<<<512, 256, 0, stream>>>(y_bf, Wt, out);
    proj_kernel<<<512, 256, 0, stream>>>(y_bf, Wt, out);
}

// Round 5
// 43.122 us; speedup vs baseline: 1.2544x; 1.2544x over previous
//
#include <hip/hip_runtime.h>
#include <math.h>

#define T_SEQ 2048
#define NH    16
#define HD    64
#define DIM   1024
#define WIN   256

typedef __attribute__((ext_vector_type(4))) float f32x4;
typedef __attribute__((ext_vector_type(8))) short s16x8;
typedef unsigned short u16;

static __device__ __forceinline__ u16 f2bf(float f) {
    unsigned u = __builtin_bit_cast(unsigned, f);
    u += 0x7fff + ((u >> 16) & 1);   // RNE; inputs finite
    return (u16)(u >> 16);
}

static __device__ __forceinline__ int fV(int d) { return (d & 7) ^ ((d >> 3) & 7); }

static __device__ __forceinline__ void gload16(const void* g, void* l) {
    __builtin_amdgcn_global_load_lds(
        (const __attribute__((address_space(1))) unsigned int*)g,
        (__attribute__((address_space(3))) unsigned int*)l, 16, 0, 0);
}

// ---------------------------------------------------------------------------
// W (K x N fp32) -> Wt (N x K bf16). Pad 69: read-side banks 2-way (free).
// ---------------------------------------------------------------------------
__global__ __launch_bounds__(256) void wconv_kernel(const float* __restrict__ W,
                                                    u16* __restrict__ Wt) {
    __shared__ float sT[64][69];
    const int t  = threadIdx.x;
    const int k0 = blockIdx.x * 64;
    const int n0 = blockIdx.y * 64;
#pragma unroll
    for (int i = 0; i < 4; ++i) {
        const int idx = i * 256 + t;
        const int kr = idx >> 4, c4 = (idx & 15) * 4;
        float4 v = *(const float4*)(W + (size_t)(k0 + kr) * DIM + n0 + c4);
        sT[kr][c4] = v.x; sT[kr][c4 + 1] = v.y; sT[kr][c4 + 2] = v.z; sT[kr][c4 + 3] = v.w;
    }
    __syncthreads();
#pragma unroll
    for (int i = 0; i < 2; ++i) {
        const int idx = i * 256 + t;
        const int nr = idx >> 3, ch = (idx & 7) * 8;
        s16x8 o;
#pragma unroll
        for (int e = 0; e < 8; ++e) o[e] = f2bf(sT[ch + e][nr]);
        *(s16x8*)(Wt + (size_t)(n0 + nr) * DIM + k0 + ch) = o;
    }
}

// ---------------------------------------------------------------------------
// Sliding-window attention, bf16 MFMA flash-style (unchanged from round 3).
// ---------------------------------------------------------------------------
__global__ __launch_bounds__(256) void attn_kernel(const float* __restrict__ qg,
                                                   const float* __restrict__ kg,
                                                   const float* __restrict__ vg,
                                                   u16* __restrict__ y) {
    __shared__ __align__(16) char sK[64 * 128];
    __shared__ __align__(16) char sV[64 * 128];
    __shared__ __align__(16) char sP[4][16 * 128];

    const int t    = threadIdx.x;
    const int lane = t & 63;
    const int w    = t >> 6;
    const int q0   = blockIdx.x * 64;
    const int h    = blockIdx.y;
    const size_t headBase = (size_t)h * T_SEQ * HD;

    const int lr = lane & 15;
    const int lg = lane >> 4;

    s16x8 qf[2];
    {
        const float* qrow = qg + headBase + (size_t)(q0 + w * 16 + lr) * HD + lg * 8;
#pragma unroll
        for (int s = 0; s < 2; ++s) {
            float4 a = *(const float4*)(qrow + 32 * s);
            float4 b = *(const float4*)(qrow + 32 * s + 4);
            s16x8 f;
            f[0] = f2bf(a.x); f[1] = f2bf(a.y); f[2] = f2bf(a.z); f[3] = f2bf(a.w);
            f[4] = f2bf(b.x); f[5] = f2bf(b.y); f[6] = f2bf(b.z); f[7] = f2bf(b.w);
            qf[s] = f;
        }
    }

    f32x4 o[4];
#pragma unroll
    for (int i = 0; i < 4; ++i) o[i] = (f32x4){0.f, 0.f, 0.f, 0.f};
    float lsum[4] = {0.f, 0.f, 0.f, 0.f};

    int lo = q0 - (WIN - 1);
    if (lo < 0) lo = 0;
    const int kc0 = lo & ~63;

    const int srow = t >> 2;
    const int sd0  = (t & 3) * 16;

    for (int kc = kc0; kc <= q0; kc += 64) {
        __syncthreads();
        {
            const float* ksrc = kg + headBase + (size_t)(kc + srow) * HD + sd0;
            float4 k0 = *(const float4*)(ksrc);
            float4 k1 = *(const float4*)(ksrc + 4);
            float4 k2 = *(const float4*)(ksrc + 8);
            float4 k3 = *(const float4*)(ksrc + 12);
            s16x8 c0, c1;
            c0[0] = f2bf(k0.x); c0[1] = f2bf(k0.y); c0[2] = f2bf(k0.z); c0[3] = f2bf(k0.w);
            c0[4] = f2bf(k1.x); c0[5] = f2bf(k1.y); c0[6] = f2bf(k1.z); c0[7] = f2bf(k1.w);
            c1[0] = f2bf(k2.x); c1[1] = f2bf(k2.y); c1[2] = f2bf(k2.z); c1[3] = f2bf(k2.w);
            c1[4] = f2bf(k3.x); c1[5] = f2bf(k3.y); c1[6] = f2bf(k3.z); c1[7] = f2bf(k3.w);
            const int swz = (srow & 7) << 4;
            *(s16x8*)(sK + srow * 128 + ((sd0 * 2) ^ swz))      = c0;
            *(s16x8*)(sK + srow * 128 + ((sd0 * 2 + 16) ^ swz)) = c1;

            const float* vsrc = vg + headBase + (size_t)(kc + srow) * HD + sd0;
            float4 v0 = *(const float4*)(vsrc);
            float4 v1 = *(const float4*)(vsrc + 4);
            float4 v2 = *(const float4*)(vsrc + 8);
            float4 v3 = *(const float4*)(vsrc + 12);
            float vv[16] = {v0.x, v0.y, v0.z, v0.w, v1.x, v1.y, v1.z, v1.w,
                            v2.x, v2.y, v2.z, v2.w, v3.x, v3.y, v3.z, v3.w};
#pragma unroll
            for (int e = 0; e < 16; ++e) {
                const int d = sd0 + e;
                *(u16*)(sV + d * 128 + ((srow * 2) ^ (fV(d) << 4))) = f2bf(vv[e]);
            }
        }
        __syncthreads();

        char* pw = sP[w];
#pragma unroll
        for (int kt = 0; kt < 4; ++kt) {
            const int krow = kt * 16 + lr;
            const int kswz = (krow & 7) << 4;
            s16x8 kf0 = *(const s16x8*)(sK + krow * 128 + ((lg * 16) ^ kswz));
            s16x8 kf1 = *(const s16x8*)(sK + krow * 128 + ((lg * 16 + 64) ^ kswz));
            f32x4 s = (f32x4){0.f, 0.f, 0.f, 0.f};
            s = __builtin_amdgcn_mfma_f32_16x16x32_bf16(qf[0], kf0, s, 0, 0, 0);
            s = __builtin_amdgcn_mfma_f32_16x16x32_bf16(qf[1], kf1, s, 0, 0, 0);
            const int key = kc + kt * 16 + lr;
#pragma unroll
            for (int r = 0; r < 4; ++r) {
                const int qrow = q0 + w * 16 + lg * 4 + r;
                float pv = 0.f;
                if (key <= qrow && key > qrow - WIN) pv = __expf(s[r] * 0.125f);
                lsum[r] += pv;
                const int prow = lg * 4 + r;
                *(u16*)(pw + prow * 128 + ((kt * 32 + lr * 2) ^ ((prow & 7) << 4))) = f2bf(pv);
            }
        }

        s16x8 pf0 = *(const s16x8*)(pw + lr * 128 + ((lg * 16) ^ ((lr & 7) << 4)));
        s16x8 pf1 = *(const s16x8*)(pw + lr * 128 + ((lg * 16 + 64) ^ ((lr & 7) << 4)));
#pragma unroll
        for (int td = 0; td < 4; ++td) {
            const int drow = td * 16 + lr;
            const int vswz = fV(drow) << 4;
            s16x8 vf0 = *(const s16x8*)(sV + drow * 128 + ((lg * 16) ^ vswz));
            s16x8 vf1 = *(const s16x8*)(sV + drow * 128 + ((lg * 16 + 64) ^ vswz));
            o[td] = __builtin_amdgcn_mfma_f32_16x16x32_bf16(pf0, vf0, o[td], 0, 0, 0);
            o[td] = __builtin_amdgcn_mfma_f32_16x16x32_bf16(pf1, vf1, o[td], 0, 0, 0);
        }
    }

#pragma unroll
    for (int m = 1; m < 16; m <<= 1) {
#pragma unroll
        for (int r = 0; r < 4; ++r) lsum[r] += __shfl_xor(lsum[r], m, 64);
    }
    float rl[4];
#pragma unroll
    for (int r = 0; r < 4; ++r) rl[r] = 1.f / lsum[r];
#pragma unroll
    for (int td = 0; td < 4; ++td)
#pragma unroll
        for (int r = 0; r < 4; ++r)
            y[(size_t)(q0 + w * 16 + lg * 4 + r) * DIM + h * HD + td * 16 + lr] =
                f2bf(o[td][r] * rl[r]);
}

// ---------------------------------------------------------------------------
// proj: out = y @ W. BM=128 BN=64 BK=64, 4 waves (2x2), wave-tile 64x32
// (16 MFMA : 12 ds_read_b128 per K-step). 3-deep LDS pipeline with counted
// vmcnt(12) -- no vmcnt(0) drain in the main loop. Per iter:
//   s_barrier                      (all waves done reading buf[(t-1)%3])
//   STAGE(buf[(t+2)%3], tile t+2)  (6 gloads/wave; overwrites buf[(t-1)%3])
//   s_waitcnt vmcnt(12)            (tile t's loads landed; t+1,t+2 in flight)
//   ds_read + MFMA from buf[t%3]
// Tail stages wrap to tiles 0/1 (stale, harmless) to keep vmcnt uniform.
// grid = 256 blocks (1/CU), XCD-chunked swizzle (2.5MB/XCD L2 footprint).
// ---------------------------------------------------------------------------
__global__ __launch_bounds__(256) void proj_kernel(const u16* __restrict__ A,
                                                   const u16* __restrict__ Bt,
                                                   float* __restrict__ out) {
    __shared__ __align__(16) char sA[3][128 * 128];  // [m][k] bf16, 16KB each
    __shared__ __align__(16) char sB[3][64 * 128];   // [n][k] bf16,  8KB each

    const int t    = threadIdx.x;
    const int lane = t & 63;
    const int w    = t >> 6;
    const int wr   = w >> 1, wc = w & 1;
    const int lr   = lane & 15, lg = lane >> 4;

    // XCD-chunked bijective swizzle (nwg=256, 8 XCDs, q=32):
    // each XCD gets 2 M-panels x 16 N-panels.
    const int id   = (int)blockIdx.x;
    const int wgid = (id & 7) * 32 + (id >> 3);
    const int m0   = (wgid >> 4) * 128;
    const int n0   = (wgid & 15) * 64;

    f32x4 acc[4][2];
#pragma unroll
    for (int i = 0; i < 4; ++i)
#pragma unroll
        for (int j = 0; j < 2; ++j) acc[i][j] = (f32x4){0.f, 0.f, 0.f, 0.f};

    // staging geometry: pass p covers rows [p*32 + w*8, +8), chunk = lane&7
    const int aRowBase = w * 8 + (lane >> 3);
    const int aChunk   = lane & 7;

#define STAGE(buf, k0)                                                                \
    do {                                                                              \
        _Pragma("unroll") for (int p = 0; p < 4; ++p) {                               \
            const int row = p * 32 + aRowBase;                                        \
            gload16(A + (size_t)(m0 + row) * DIM + (k0) + ((aChunk ^ (row & 7)) << 3),\
                    sA[buf] + p * 4096 + w * 1024);                                   \
        }                                                                             \
        _Pragma("unroll") for (int p = 0; p < 2; ++p) {                               \
            const int row = p * 32 + aRowBase;                                        \
            gload16(Bt + (size_t)(n0 + row) * DIM + (k0) + ((aChunk ^ (row & 7)) << 3),\
                    sB[buf] + p * 4096 + w * 1024);                                   \
        }                                                                             \
    } while (0)

    STAGE(0, 0);
    STAGE(1, 64);

#pragma unroll
    for (int kt = 0; kt < DIM / 64; ++kt) {
        const int cur = kt % 3;
        const int nxt = (kt + 2) % 3;
        const int knxt = ((kt + 2) & 15) * 64;  // wraps at tail: stale reload, harmless

        __builtin_amdgcn_s_barrier();           // compute(kt-1) reads done before overwrite
        STAGE(nxt, knxt);
        asm volatile("s_waitcnt vmcnt(12)" ::: "memory");  // tile kt landed (all waves)

        s16x8 af[2][4], bfr[2][2];
#pragma unroll
        for (int kh = 0; kh < 2; ++kh) {
#pragma unroll
            for (int mi = 0; mi < 4; ++mi) {
                const int row = wr * 64 + mi * 16 + lr;
                const int cc  = kh * 4 + lg;
                af[kh][mi] = *(const s16x8*)(sA[cur] + row * 128 + ((cc ^ (row & 7)) << 4));
            }
#pragma unroll
            for (int ni = 0; ni < 2; ++ni) {
                const int row = wc * 32 + ni * 16 + lr;
                const int cc  = kh * 4 + lg;
                bfr[kh][ni] = *(const s16x8*)(sB[cur] + row * 128 + ((cc ^ (row & 7)) << 4));
            }
        }
#pragma unroll
        for (int kh = 0; kh < 2; ++kh)
#pragma unroll
            for (int mi = 0; mi < 4; ++mi)
#pragma unroll
                for (int ni = 0; ni < 2; ++ni)
                    acc[mi][ni] = __builtin_amdgcn_mfma_f32_16x16x32_bf16(
                        af[kh][mi], bfr[kh][ni], acc[mi][ni], 0, 0, 0);
    }
#undef STAGE

#pragma unroll
    for (int mi = 0; mi < 4; ++mi)
#pragma unroll
        for (int ni = 0; ni < 2; ++ni)
#pragma unroll
            for (int r = 0; r < 4; ++r)
                out[(size_t)(m0 + wr * 64 + mi * 16 + lg * 4 + r) * DIM +
                    n0 + wc * 32 + ni * 16 + lr] = acc[mi][ni][r];
}

extern "C" void kernel_launch(void* const* d_in, const int* in_sizes, int n_in,
                              void* d_out, int out_size, void* d_ws, size_t ws_size,
                              hipStream_t stream) {
    const float* q = (const float*)d_in[0];
    const float* k = (const float*)d_in[1];
    const float* v = (const float*)d_in[2];
    const float* W = (const float*)d_in[3];
    float* out = (float*)d_out;
    u16* y_bf = (u16*)d_ws;                       // (T, DIM) bf16 = 4MB
    u16* Wt   = (u16*)d_ws + (size_t)T_SEQ * DIM; // (DIM, DIM) bf16 = 2MB

    dim3 gW(DIM / 64, DIM / 64);
    wconv_kernel<<<gW, 256, 0, stream>>>(W, Wt);

    dim3 gA(T_SEQ / 64, NH);
    attn_kernel<<<gA, 256, 0, stream>>>(q, k, v, y_bf);

    proj_kernel<<<256, 256, 0, stream>>>(y_bf, Wt, out);
}

// Round 6
// 37.300 us; speedup vs baseline: 1.4501x; 1.1561x over previous
//
#include <hip/hip_runtime.h>
#include <math.h>

#define T_SEQ 2048
#define NH    16
#define HD    64
#define DIM   1024
#define WIN   256

typedef __attribute__((ext_vector_type(4))) float f32x4;
typedef __attribute__((ext_vector_type(8))) short s16x8;
typedef unsigned short u16;

static __device__ __forceinline__ u16 f2bf(float f) {
    unsigned u = __builtin_bit_cast(unsigned, f);
    u += 0x7fff + ((u >> 16) & 1);   // RNE; inputs finite
    return (u16)(u >> 16);
}

static __device__ __forceinline__ int fV(int d) { return (d & 7) ^ ((d >> 3) & 7); }

static __device__ __forceinline__ void gload16(const void* g, void* l) {
    __builtin_amdgcn_global_load_lds(
        (const __attribute__((address_space(1))) unsigned int*)g,
        (__attribute__((address_space(3))) unsigned int*)l, 16, 0, 0);
}

// ---------------------------------------------------------------------------
// Fused prep kernel. blocks [0,256): W transpose+bf16. blocks [256,768): attn.
// Both parts are the round-5 kernels verbatim (independent inputs/outputs).
// ---------------------------------------------------------------------------
__global__ __launch_bounds__(256) void prep_kernel(const float* __restrict__ W,
                                                   u16* __restrict__ Wt,
                                                   const float* __restrict__ qg,
                                                   const float* __restrict__ kg,
                                                   const float* __restrict__ vg,
                                                   u16* __restrict__ y) {
    __shared__ __align__(16) char smem[4 * 16 * 128 + 2 * 64 * 128];  // 24KB (attn view)
    const int bid = (int)blockIdx.x;
    const int t   = threadIdx.x;

    if (bid < 256) {
        // ---- wconv: W (K x N fp32) -> Wt (N x K bf16) ----
        float(*sT)[69] = (float(*)[69])smem;  // 64*69*4 = 17.2KB < 24KB
        const int k0 = (bid & 15) * 64;
        const int n0 = (bid >> 4) * 64;
#pragma unroll
        for (int i = 0; i < 4; ++i) {
            const int idx = i * 256 + t;
            const int kr = idx >> 4, c4 = (idx & 15) * 4;
            float4 v = *(const float4*)(W + (size_t)(k0 + kr) * DIM + n0 + c4);
            sT[kr][c4] = v.x; sT[kr][c4 + 1] = v.y; sT[kr][c4 + 2] = v.z; sT[kr][c4 + 3] = v.w;
        }
        __syncthreads();
#pragma unroll
        for (int i = 0; i < 2; ++i) {
            const int idx = i * 256 + t;
            const int nr = idx >> 3, ch = (idx & 7) * 8;
            s16x8 o;
#pragma unroll
            for (int e = 0; e < 8; ++e) o[e] = f2bf(sT[ch + e][nr]);
            *(s16x8*)(Wt + (size_t)(n0 + nr) * DIM + k0 + ch) = o;
        }
        return;
    }

    // ---- attention ----
    char* sK = smem;                     // 64*128 bf16 [key][d], swz (key&7)<<4
    char* sV = smem + 64 * 128;          // 64*128 bf16 [d][key], swz fV(d)<<4
    char* sPb = smem + 2 * 64 * 128;     // 4 x 16*128 per-wave P

    const int ab   = bid - 256;
    const int lane = t & 63;
    const int w    = t >> 6;
    const int q0   = (ab & 31) * 64;
    const int h    = ab >> 5;
    const size_t headBase = (size_t)h * T_SEQ * HD;

    const int lr = lane & 15;
    const int lg = lane >> 4;

    s16x8 qf[2];
    {
        const float* qrow = qg + headBase + (size_t)(q0 + w * 16 + lr) * HD + lg * 8;
#pragma unroll
        for (int s = 0; s < 2; ++s) {
            float4 a = *(const float4*)(qrow + 32 * s);
            float4 b = *(const float4*)(qrow + 32 * s + 4);
            s16x8 f;
            f[0] = f2bf(a.x); f[1] = f2bf(a.y); f[2] = f2bf(a.z); f[3] = f2bf(a.w);
            f[4] = f2bf(b.x); f[5] = f2bf(b.y); f[6] = f2bf(b.z); f[7] = f2bf(b.w);
            qf[s] = f;
        }
    }

    f32x4 o[4];
#pragma unroll
    for (int i = 0; i < 4; ++i) o[i] = (f32x4){0.f, 0.f, 0.f, 0.f};
    float lsum[4] = {0.f, 0.f, 0.f, 0.f};

    int lo = q0 - (WIN - 1);
    if (lo < 0) lo = 0;
    const int kc0 = lo & ~63;

    const int srow = t >> 2;
    const int sd0  = (t & 3) * 16;

    for (int kc = kc0; kc <= q0; kc += 64) {
        __syncthreads();
        {
            const float* ksrc = kg + headBase + (size_t)(kc + srow) * HD + sd0;
            float4 k0 = *(const float4*)(ksrc);
            float4 k1 = *(const float4*)(ksrc + 4);
            float4 k2 = *(const float4*)(ksrc + 8);
            float4 k3 = *(const float4*)(ksrc + 12);
            s16x8 c0, c1;
            c0[0] = f2bf(k0.x); c0[1] = f2bf(k0.y); c0[2] = f2bf(k0.z); c0[3] = f2bf(k0.w);
            c0[4] = f2bf(k1.x); c0[5] = f2bf(k1.y); c0[6] = f2bf(k1.z); c0[7] = f2bf(k1.w);
            c1[0] = f2bf(k2.x); c1[1] = f2bf(k2.y); c1[2] = f2bf(k2.z); c1[3] = f2bf(k2.w);
            c1[4] = f2bf(k3.x); c1[5] = f2bf(k3.y); c1[6] = f2bf(k3.z); c1[7] = f2bf(k3.w);
            const int swz = (srow & 7) << 4;
            *(s16x8*)(sK + srow * 128 + ((sd0 * 2) ^ swz))      = c0;
            *(s16x8*)(sK + srow * 128 + ((sd0 * 2 + 16) ^ swz)) = c1;

            const float* vsrc = vg + headBase + (size_t)(kc + srow) * HD + sd0;
            float4 v0 = *(const float4*)(vsrc);
            float4 v1 = *(const float4*)(vsrc + 4);
            float4 v2 = *(const float4*)(vsrc + 8);
            float4 v3 = *(const float4*)(vsrc + 12);
            float vv[16] = {v0.x, v0.y, v0.z, v0.w, v1.x, v1.y, v1.z, v1.w,
                            v2.x, v2.y, v2.z, v2.w, v3.x, v3.y, v3.z, v3.w};
#pragma unroll
            for (int e = 0; e < 16; ++e) {
                const int d = sd0 + e;
                *(u16*)(sV + d * 128 + ((srow * 2) ^ (fV(d) << 4))) = f2bf(vv[e]);
            }
        }
        __syncthreads();

        char* pw = sPb + w * 16 * 128;
#pragma unroll
        for (int kt = 0; kt < 4; ++kt) {
            const int krow = kt * 16 + lr;
            const int kswz = (krow & 7) << 4;
            s16x8 kf0 = *(const s16x8*)(sK + krow * 128 + ((lg * 16) ^ kswz));
            s16x8 kf1 = *(const s16x8*)(sK + krow * 128 + ((lg * 16 + 64) ^ kswz));
            f32x4 s = (f32x4){0.f, 0.f, 0.f, 0.f};
            s = __builtin_amdgcn_mfma_f32_16x16x32_bf16(qf[0], kf0, s, 0, 0, 0);
            s = __builtin_amdgcn_mfma_f32_16x16x32_bf16(qf[1], kf1, s, 0, 0, 0);
            const int key = kc + kt * 16 + lr;
#pragma unroll
            for (int r = 0; r < 4; ++r) {
                const int qrow = q0 + w * 16 + lg * 4 + r;
                float pv = 0.f;
                if (key <= qrow && key > qrow - WIN) pv = __expf(s[r] * 0.125f);
                lsum[r] += pv;
                const int prow = lg * 4 + r;
                *(u16*)(pw + prow * 128 + ((kt * 32 + lr * 2) ^ ((prow & 7) << 4))) = f2bf(pv);
            }
        }

        s16x8 pf0 = *(const s16x8*)(pw + lr * 128 + ((lg * 16) ^ ((lr & 7) << 4)));
        s16x8 pf1 = *(const s16x8*)(pw + lr * 128 + ((lg * 16 + 64) ^ ((lr & 7) << 4)));
#pragma unroll
        for (int td = 0; td < 4; ++td) {
            const int drow = td * 16 + lr;
            const int vswz = fV(drow) << 4;
            s16x8 vf0 = *(const s16x8*)(sV + drow * 128 + ((lg * 16) ^ vswz));
            s16x8 vf1 = *(const s16x8*)(sV + drow * 128 + ((lg * 16 + 64) ^ vswz));
            o[td] = __builtin_amdgcn_mfma_f32_16x16x32_bf16(pf0, vf0, o[td], 0, 0, 0);
            o[td] = __builtin_amdgcn_mfma_f32_16x16x32_bf16(pf1, vf1, o[td], 0, 0, 0);
        }
    }

#pragma unroll
    for (int m = 1; m < 16; m <<= 1) {
#pragma unroll
        for (int r = 0; r < 4; ++r) lsum[r] += __shfl_xor(lsum[r], m, 64);
    }
    float rl[4];
#pragma unroll
    for (int r = 0; r < 4; ++r) rl[r] = 1.f / lsum[r];
#pragma unroll
    for (int td = 0; td < 4; ++td)
#pragma unroll
        for (int r = 0; r < 4; ++r)
            y[(size_t)(q0 + w * 16 + lg * 4 + r) * DIM + h * HD + td * 16 + lr] =
                f2bf(o[td][r] * rl[r]);
}

// ---------------------------------------------------------------------------
// proj: out = y @ W. BM=BN=BK=64, 4 waves (2x2), wave-tile 32x32.
// R4's occupancy geometry (grid 512 = 2 blocks/CU; LDS 48KB -> both fit)
// + 3-deep counted-vmcnt pipeline, race-free order:
//   STAGE(t+2) ; s_waitcnt vmcnt(8) ; s_barrier   <- ALL waves' tile-t landed
//   ds_read buf[t%3] ; setprio(1) MFMA setprio(0) ; s_barrier
// No vmcnt(0) drain in the loop. Tail stages wrap (stale, harmless).
// ---------------------------------------------------------------------------
__global__ __launch_bounds__(256) void proj_kernel(const u16* __restrict__ A,
                                                   const u16* __restrict__ Bt,
                                                   float* __restrict__ out) {
    __shared__ __align__(16) char sA[3][64 * 128];  // [m][k] bf16, 8KB each
    __shared__ __align__(16) char sB[3][64 * 128];  // [n][k] bf16, 8KB each

    const int t    = threadIdx.x;
    const int lane = t & 63;
    const int w    = t >> 6;
    const int wr   = w >> 1, wc = w & 1;
    const int lr   = lane & 15, lg = lane >> 4;

    // XCD-chunked bijective swizzle (nwg=512, 8 XCDs, q=64):
    // each XCD: 4 M-panels x 16 N-panels -> A 512KB + B 2MB = 2.5MB L2 set.
    const int id   = (int)blockIdx.x;
    const int wgid = (id & 7) * 64 + (id >> 3);
    const int m0   = (wgid >> 4) * 64;
    const int n0   = (wgid & 15) * 64;

    f32x4 acc[2][2];
#pragma unroll
    for (int i = 0; i < 2; ++i)
#pragma unroll
        for (int j = 0; j < 2; ++j) acc[i][j] = (f32x4){0.f, 0.f, 0.f, 0.f};

    // staging: pass p covers rows [p*32 + w*8, +8), lane chunk = lane&7
    const int aRowBase = w * 8 + (lane >> 3);
    const int aChunk   = lane & 7;

#define STAGE(buf, k0)                                                                \
    do {                                                                              \
        _Pragma("unroll") for (int p = 0; p < 2; ++p) {                               \
            const int row = p * 32 + aRowBase;                                        \
            gload16(A + (size_t)(m0 + row) * DIM + (k0) + ((aChunk ^ (row & 7)) << 3),\
                    sA[buf] + p * 4096 + w * 1024);                                   \
            gload16(Bt + (size_t)(n0 + row) * DIM + (k0) + ((aChunk ^ (row & 7)) << 3),\
                    sB[buf] + p * 4096 + w * 1024);                                   \
        }                                                                             \
    } while (0)

    STAGE(0, 0);
    STAGE(1, 64);

#pragma unroll
    for (int kt = 0; kt < DIM / 64; ++kt) {
        const int cur  = kt % 3;
        const int nxt  = (kt + 2) % 3;
        const int knxt = ((kt + 2) & 15) * 64;  // tail wraps: stale reload, harmless

        STAGE(nxt, knxt);                        // overwrites buf[(kt-1)%3]; all waves
                                                 // passed end-barrier of iter kt-1
        asm volatile("s_waitcnt vmcnt(8)" ::: "memory");  // own tile-kt loads landed
        __builtin_amdgcn_s_barrier();            // => ALL waves' tile-kt loads landed

        s16x8 af[2][2], bfr[2][2];
#pragma unroll
        for (int kh = 0; kh < 2; ++kh) {
#pragma unroll
            for (int mi = 0; mi < 2; ++mi) {
                const int row = wr * 32 + mi * 16 + lr;
                const int cc  = kh * 4 + lg;
                af[kh][mi] = *(const s16x8*)(sA[cur] + row * 128 + ((cc ^ (row & 7)) << 4));
            }
#pragma unroll
            for (int ni = 0; ni < 2; ++ni) {
                const int row = wc * 32 + ni * 16 + lr;
                const int cc  = kh * 4 + lg;
                bfr[kh][ni] = *(const s16x8*)(sB[cur] + row * 128 + ((cc ^ (row & 7)) << 4));
            }
        }
        __builtin_amdgcn_s_setprio(1);
#pragma unroll
        for (int kh = 0; kh < 2; ++kh)
#pragma unroll
            for (int mi = 0; mi < 2; ++mi)
#pragma unroll
                for (int ni = 0; ni < 2; ++ni)
                    acc[mi][ni] = __builtin_amdgcn_mfma_f32_16x16x32_bf16(
                        af[kh][mi], bfr[kh][ni], acc[mi][ni], 0, 0, 0);
        __builtin_amdgcn_s_setprio(0);
        __builtin_amdgcn_s_barrier();            // reads of buf[cur] done before
                                                 // iter kt+1's STAGE overwrites it
    }
#undef STAGE

#pragma unroll
    for (int mi = 0; mi < 2; ++mi)
#pragma unroll
        for (int ni = 0; ni < 2; ++ni)
#pragma unroll
            for (int r = 0; r < 4; ++r)
                out[(size_t)(m0 + wr * 32 + mi * 16 + lg * 4 + r) * DIM +
                    n0 + wc * 32 + ni * 16 + lr] = acc[mi][ni][r];
}

extern "C" void kernel_launch(void* const* d_in, const int* in_sizes, int n_in,
                              void* d_out, int out_size, void* d_ws, size_t ws_size,
                              hipStream_t stream) {
    const float* q = (const float*)d_in[0];
    const float* k = (const float*)d_in[1];
    const float* v = (const float*)d_in[2];
    const float* W = (const float*)d_in[3];
    float* out = (float*)d_out;
    u16* y_bf = (u16*)d_ws;                       // (T, DIM) bf16 = 4MB
    u16* Wt   = (u16*)d_ws + (size_t)T_SEQ * DIM; // (DIM, DIM) bf16 = 2MB

    prep_kernel<<<768, 256, 0, stream>>>(W, Wt, q, k, v, y_bf);
    proj_kernel<<<512, 256, 0, stream>>>(y_bf, Wt, out);
}